// Round 13
// baseline (76.417 us; speedup 1.0000x reference)
//
#include <hip/hip_runtime.h>
#include <stdint.h>

// DSN few-shot classifier, MI355X.
// out[q][w] = log_softmax_w( s_w ),  s_w = z_w^T Ghat_w z_w,
// z_w = M_w^T q (raw support dots),  Ghat = G^{-1} - vhat vhat^T.
//
// R12: the 10x10 solve is REDUNDANT PER EPILOGUE BLOCK (256 blocks x 64
// threads, single-wave barriers). R11 proved a lonely solve chain costs
// ~60us regardless of code shape (idle-GPU latency/DVFS law); running it
// 256x redundantly on a busy device pays it once, in parallel.
//
// ws layout:
//   [0,      4000)   G  : 5*100 double
//   [8192,   172032) P  : 80*1024 bf16 (way w rows 16w..16w+9; rest zero)
//   [262144, 5505024) Z : [80][16384] float

typedef __attribute__((ext_vector_type(4))) float f32x4;
typedef __attribute__((ext_vector_type(8))) short s16x8;

#define WS_G_OFF    0
#define WS_P_OFF    8192
#define WS_Z_OFF    262144

__device__ __forceinline__ unsigned short f2bf(float f) {
  unsigned int u = __float_as_uint(f);
  u += 0x7FFFu + ((u >> 16) & 1u);   // round-to-nearest-even
  return (unsigned short)(u >> 16);
}

// int64 vs int32 one-hot labels detection (validated R0).
__device__ __forceinline__ bool labels_int64(const int* L) {
  int cnt = 0; bool oddz = true;
  #pragma unroll
  for (int t = 0; t < 20; ++t) {
    int v = L[t];
    if (t & 1) { if (v) oddz = false; }
    else       { if (v) cnt++; }
  }
  return oddz && (cnt == 2);
}

__device__ __forceinline__ int cls_of(const int* L, bool is64, int i) {
  int best = -0x7fffffff, c = 0;
  #pragma unroll
  for (int j = 0; j < 5; ++j) {
    int v = is64 ? L[i * 10 + 2 * j] : L[i * 5 + j];
    if (v > best) { best = v; c = j; }
  }
  return c;
}

// ---- Kernel 1: gram (blocks 0..68) + pack P (blocks 69..148) --------------
__global__ __launch_bounds__(256) void dsn_prep(const float* __restrict__ support,
                                                const int* __restrict__ labels,
                                                double* __restrict__ G,
                                                unsigned short* __restrict__ P) {
  int b = blockIdx.x;
  bool is64 = labels_int64(labels);

  if (b < 69) {                        // ---- gram: one wave per (w,a,b) pair
    int wid  = b * 4 + (threadIdx.x >> 6);
    int lane = threadIdx.x & 63;
    if (wid >= 275) return;
    int w = wid / 55, p = wid % 55;
    int a = 0;
    while (p >= 10 - a) { p -= 10 - a; a++; }
    int bb = a + p;

    int myc = (lane < 50) ? cls_of(labels, is64, lane) : -1;
    unsigned long long mask = __ballot(lane < 50 && myc == w);

    unsigned long long m = mask;
    for (int i = 0; i < a; ++i) m &= m - 1;
    int ia = __ffsll((unsigned long long)m) - 1;
    m = mask;
    for (int i = 0; i < bb; ++i) m &= m - 1;
    int ib = __ffsll((unsigned long long)m) - 1;

    const float* A = support + ia * 1024;
    const float* B = support + ib * 1024;
    double acc = 0.0;
    #pragma unroll
    for (int i = 0; i < 16; ++i) {
      int d = lane + 64 * i;
      acc += (double)A[d] * (double)B[d];
    }
    #pragma unroll
    for (int off = 32; off > 0; off >>= 1) acc += __shfl_xor(acc, off);
    if (lane == 0) {
      G[(w * 10 + a) * 10 + bb] = acc;
      G[(w * 10 + bb) * 10 + a] = acc;
    }
  } else {                             // ---- pack: one block per P row
    int r = b - 69;                    // 0..79
    int w = r >> 4, kk = r & 15;
    int t = threadIdx.x;
    unsigned short* Prow = P + r * 1024;
    if (kk >= 10) {                    // zero-pad rows (block-uniform)
      #pragma unroll
      for (int j = 0; j < 4; ++j) Prow[t + 256 * j] = 0;
      return;
    }
    __shared__ int sid;
    if (t < 64) {
      int myc = (t < 50) ? cls_of(labels, is64, t) : -1;
      unsigned long long mask = __ballot(t < 50 && myc == w);
      if (t == 0) {
        unsigned long long m = mask;
        for (int z = 0; z < kk; ++z) m &= m - 1;
        sid = __ffsll(m) - 1;
      }
    }
    __syncthreads();
    const float* src = support + (size_t)sid * 1024;
    #pragma unroll
    for (int j = 0; j < 4; ++j) Prow[t + 256 * j] = f2bf(src[t + 256 * j]);
  }
}

// ---- Kernel 2: pure Z-GEMM, 256 blocks ------------------------------------
// Z[s_global][q] = sum_d P[s_global][d] * q[d], s_global = w*16 + s.
__global__ __launch_bounds__(256) void dsn_zgemm(const float* __restrict__ query,
                                                 const unsigned short* __restrict__ P,
                                                 float* __restrict__ Z) {
  int wid  = blockIdx.x * 4 + (threadIdx.x >> 6);
  int lane = threadIdx.x & 63;
  int q0   = wid * 16;
  int qrow = lane & 15;
  int kbase = (lane >> 4) * 8;

  const float* qp = query + (size_t)(q0 + qrow) * 1024 + kbase;
  const unsigned short* up = P + qrow * 1024 + kbase;

  f32x4 acc[5];
  #pragma unroll
  for (int w = 0; w < 5; ++w) acc[w] = (f32x4){0.f, 0.f, 0.f, 0.f};

  #pragma unroll 4
  for (int kt = 0; kt < 32; ++kt) {
    const float* qk = qp + kt * 32;
    f32x4 lo = *(const f32x4*)qk;
    f32x4 hi = *(const f32x4*)(qk + 4);
    s16x8 bf;
    bf[0] = (short)f2bf(lo[0]); bf[1] = (short)f2bf(lo[1]);
    bf[2] = (short)f2bf(lo[2]); bf[3] = (short)f2bf(lo[3]);
    bf[4] = (short)f2bf(hi[0]); bf[5] = (short)f2bf(hi[1]);
    bf[6] = (short)f2bf(hi[2]); bf[7] = (short)f2bf(hi[3]);
    const unsigned short* uk = up + kt * 32;
    #pragma unroll
    for (int w = 0; w < 5; ++w) {
      s16x8 av = *(const s16x8*)(uk + w * 16384);   // row w*16 + qrow
      acc[w] = __builtin_amdgcn_mfma_f32_16x16x32_bf16(av, bf, acc[w], 0, 0, 0);
    }
  }

  // store Z: D[row=s][col=q]; row = (lane>>4)*4 + reg, col = lane&15 (m89)
  int rowbase = (lane >> 4) * 4;
  #pragma unroll
  for (int w = 0; w < 5; ++w) {
    #pragma unroll
    for (int r = 0; r < 4; ++r)
      Z[(size_t)(w * 16 + rowbase + r) * 16384 + q0 + qrow] = acc[w][r];
  }
}

// ---- Kernel 3: post — redundant 5-way solve + quadratic forms -------------
// 256 blocks x 64 threads (single wave). Lane t owns LDS entries 8t..8t+7 of
// the 5x(10x10) matrices. All barriers are single-wave (cheap). Numerics =
// R10/R11 validated: NS G^{-1/2} (6 it) + 8 power-squarings for v_min.
__global__ __launch_bounds__(64) void dsn_post(const double* __restrict__ G,
                                               const float* __restrict__ Z,
                                               float* __restrict__ out) {
  __shared__ float Gf[500], Ys[500], Zs[500], Ps[500];
  __shared__ float red[5][10];
  __shared__ float cc[5], mm[5], dn[5];
  __shared__ float vv[5][10];
  __shared__ int   jm[5];

  int t = threadIdx.x;
  // per-lane entry metadata (compile-time unrolled -> registers)
  int ew[8], eio[8], ejo[8], eii[8], ejj[8];
  bool ea[8];
  #pragma unroll
  for (int u = 0; u < 8; ++u) {
    int e = 8 * t + u;
    ea[u] = (e < 500);
    int ec = ea[u] ? e : 0;
    int w = ec / 100, rem = ec % 100, i = rem / 10, j = rem % 10;
    ew[u] = w; eii[u] = i; ejj[u] = j;
    eio[u] = w * 100 + i * 10;          // row-i base
    ejo[u] = w * 100 + j;               // col-j base (stride 10)
  }

  #pragma unroll
  for (int u = 0; u < 8; ++u)
    if (ea[u]) Gf[8 * t + u] = (float)G[8 * t + u];
  __syncthreads();

  // c_w = Gershgorin upper bound on lambda_max
  if (t < 50) {
    int w = t / 10, i = t % 10;
    float r = 0.f;
    #pragma unroll
    for (int k = 0; k < 10; ++k) r += fabsf(Gf[w * 100 + i * 10 + k]);
    red[w][i] = r;
  }
  __syncthreads();
  if (t < 5) {
    float m = red[t][0];
    #pragma unroll
    for (int k = 1; k < 10; ++k) m = fmaxf(m, red[t][k]);
    cc[t] = m;
  }
  __syncthreads();
  float cinvu[8];
  #pragma unroll
  for (int u = 0; u < 8; ++u) cinvu[u] = 1.f / cc[ew[u]];

  // init: Y = S = G/c, Z = I
  #pragma unroll
  for (int u = 0; u < 8; ++u) {
    int e = 8 * t + u;
    if (ea[u]) {
      Ys[e] = Gf[e] * cinvu[u];
      Zs[e] = (eii[u] == ejj[u]) ? 1.f : 0.f;
    }
  }
  __syncthreads();

  // Newton-Schulz (6 iters): Y->S^{1/2}, Z->S^{-1/2}
  #pragma unroll 1
  for (int it = 0; it < 6; ++it) {
    #pragma unroll
    for (int u = 0; u < 8; ++u) {
      if (ea[u]) {
        float p = 0.f;
        #pragma unroll
        for (int k = 0; k < 10; ++k) p += Zs[eio[u] + k] * Ys[ejo[u] + 10 * k];
        Ps[8 * t + u] = p;
      }
    }
    __syncthreads();
    float yn[8], zn[8];
    #pragma unroll
    for (int u = 0; u < 8; ++u) {
      if (ea[u]) {
        float ay = 0.f, az = 0.f;
        #pragma unroll
        for (int k = 0; k < 10; ++k) {
          ay += Ys[eio[u] + k] * Ps[ejo[u] + 10 * k];
          az += Ps[eio[u] + k] * Zs[ejo[u] + 10 * k];
        }
        yn[u] = 1.5f * Ys[8 * t + u] - 0.5f * ay;
        zn[u] = 1.5f * Zs[8 * t + u] - 0.5f * az;
      }
    }
    __syncthreads();
    #pragma unroll
    for (int u = 0; u < 8; ++u)
      if (ea[u]) { Ys[8 * t + u] = yn[u]; Zs[8 * t + u] = zn[u]; }
    __syncthreads();
  }

  // v_min via repeated squaring of T = I - S (Ys reused for T)
  #pragma unroll
  for (int u = 0; u < 8; ++u) {
    int e = 8 * t + u;
    if (ea[u]) Ys[e] = ((eii[u] == ejj[u]) ? 1.f : 0.f) - Gf[e] * cinvu[u];
  }
  __syncthreads();
  #pragma unroll 1
  for (int sq = 0; sq < 8; ++sq) {
    #pragma unroll
    for (int u = 0; u < 8; ++u) {
      if (ea[u]) {
        float p = 0.f;
        #pragma unroll
        for (int k = 0; k < 10; ++k) p += Ys[eio[u] + k] * Ys[ejo[u] + 10 * k];
        Ps[8 * t + u] = p;
      }
    }
    __syncthreads();
    if (t < 50) {
      int w = t / 10, i = t % 10;
      float m = 0.f;
      #pragma unroll
      for (int k = 0; k < 10; ++k) m = fmaxf(m, fabsf(Ps[w * 100 + i * 10 + k]));
      red[w][i] = m;
    }
    __syncthreads();
    if (t < 5) {
      float m = red[t][0];
      #pragma unroll
      for (int k = 1; k < 10; ++k) m = fmaxf(m, red[t][k]);
      mm[t] = 1.f / m;
    }
    __syncthreads();
    #pragma unroll
    for (int u = 0; u < 8; ++u) {
      int e = 8 * t + u;
      if (ea[u]) Ys[e] = Ps[e] * mm[ew[u]];
    }
    __syncthreads();
  }

  // v = column of max diagonal; denom = v^T G v
  if (t < 5) {
    int best = 0; float bv = Ys[t * 100];
    #pragma unroll
    for (int k = 1; k < 10; ++k) {
      float dk = Ys[t * 100 + k * 10 + k];
      if (dk > bv) { bv = dk; best = k; }
    }
    jm[t] = best;
  }
  __syncthreads();
  if (t < 50) {
    int w = t / 10, i = t % 10;
    vv[w][i] = Ys[w * 100 + i * 10 + jm[w]];
  }
  __syncthreads();
  if (t < 5) {
    float denom = 0.f;
    #pragma unroll
    for (int a2 = 0; a2 < 10; ++a2) {
      float gv = 0.f;
      #pragma unroll
      for (int k = 0; k < 10; ++k) gv += Gf[t * 100 + a2 * 10 + k] * vv[t][k];
      denom += vv[t][a2] * gv;
    }
    dn[t] = rsqrtf(denom);
  }
  __syncthreads();

  // Ghat = Zs*Zs/c - vhat vhat^T  -> store into Ps
  #pragma unroll
  for (int u = 0; u < 8; ++u) {
    if (ea[u]) {
      float p = 0.f;
      #pragma unroll
      for (int k = 0; k < 10; ++k) p += Zs[eio[u] + k] * Zs[ejo[u] + 10 * k];
      float rs = dn[ew[u]];
      Ps[8 * t + u] = p * cinvu[u] -
                      (vv[ew[u]][eii[u]] * rs) * (vv[ew[u]][ejj[u]] * rs);
    }
  }
  __syncthreads();

  // ---- epilogue: 64 queries (one per lane), quadratic forms + log_softmax
  int q = blockIdx.x * 64 + t;
  float zv[50];
  #pragma unroll
  for (int w = 0; w < 5; ++w)
    #pragma unroll
    for (int s = 0; s < 10; ++s)
      zv[w * 10 + s] = Z[(size_t)(w * 16 + s) * 16384 + q];   // coalesced

  float sv[5];
  #pragma unroll
  for (int w = 0; w < 5; ++w) {
    float s = 0.f;
    #pragma unroll
    for (int i = 0; i < 10; ++i) {
      float gz = 0.f;
      #pragma unroll
      for (int j = 0; j < 10; ++j) gz += Ps[w * 100 + i * 10 + j] * zv[w * 10 + j];
      s += zv[w * 10 + i] * gz;
    }
    sv[w] = s;
  }
  float mx = fmaxf(fmaxf(fmaxf(sv[0], sv[1]), fmaxf(sv[2], sv[3])), sv[4]);
  float sum = 0.f;
  #pragma unroll
  for (int w = 0; w < 5; ++w) sum += expf(sv[w] - mx);
  float lse = mx + logf(sum);
  float* o = out + (size_t)q * 5;
  #pragma unroll
  for (int w = 0; w < 5; ++w) o[w] = sv[w] - lse;
}

extern "C" void kernel_launch(void* const* d_in, const int* in_sizes, int n_in,
                              void* d_out, int out_size, void* d_ws, size_t ws_size,
                              hipStream_t stream) {
  const float* support = (const float*)d_in[0];
  const int*   labels  = (const int*)d_in[1];
  const float* query   = (const float*)d_in[2];
  float* out = (float*)d_out;
  char* ws = (char*)d_ws;

  double*         G = (double*)(ws + WS_G_OFF);
  unsigned short* P = (unsigned short*)(ws + WS_P_OFF);
  float*          Z = (float*)(ws + WS_Z_OFF);

  int nq = in_sizes[2] / 1024;          // 16384
  int gemm_blocks = nq / 64;            // 256
  int post_blocks = nq / 64;            // 256

  hipLaunchKernelGGL(dsn_prep,  dim3(149), dim3(256), 0, stream, support, labels, G, P);
  hipLaunchKernelGGL(dsn_zgemm, dim3(gemm_blocks), dim3(256), 0, stream, query, P, Z);
  hipLaunchKernelGGL(dsn_post,  dim3(post_blocks), dim3(64), 0, stream, G, Z, out);
}

// Round 14
// 43.262 us; speedup vs baseline: 1.7664x; 1.7664x over previous
//
#include <hip/hip_runtime.h>
#include <stdint.h>

// DSN few-shot classifier, MI355X.
// out[q][w] = log_softmax_w( s_w ),  s_w = z_w^T Ghat_w z_w,
// z_w = M_w^T q (raw support dots),  Ghat = G^{-1} - v v^T/(v^T G v).
//
// R13: solve made ~10x cheaper (sweep-operator G^{-1}: 10 rank-1 steps, vs
// Newton-Schulz's 20 matmul phases; v_min via 7 diag-normalized squarings of
// Ginv + 2 refine matvecs) and hidden: solve = blocks 0-4 of the GEMM kernel
// (single-wave blocks, R10-proven sync shape), concurrent with 1024 GEMM
// blocks at ramped clock.
//
// ws layout:
//   [0,      4000)   G    : 5*100 double
//   [4096,   6096)   Ghat : 5*100 float
//   [8192,   172032) P    : 80*1024 bf16 (way w rows 16w..16w+9; rest zero)
//   [262144, 5505024) Z   : [80][16384] float

typedef __attribute__((ext_vector_type(4))) float f32x4;
typedef __attribute__((ext_vector_type(8))) short s16x8;

#define WS_G_OFF    0
#define WS_GH_OFF   4096
#define WS_P_OFF    8192
#define WS_Z_OFF    262144

__device__ __forceinline__ unsigned short f2bf(float f) {
  unsigned int u = __float_as_uint(f);
  u += 0x7FFFu + ((u >> 16) & 1u);   // round-to-nearest-even
  return (unsigned short)(u >> 16);
}

// int64 vs int32 one-hot labels detection (validated R0).
__device__ __forceinline__ bool labels_int64(const int* L) {
  int cnt = 0; bool oddz = true;
  #pragma unroll
  for (int t = 0; t < 20; ++t) {
    int v = L[t];
    if (t & 1) { if (v) oddz = false; }
    else       { if (v) cnt++; }
  }
  return oddz && (cnt == 2);
}

__device__ __forceinline__ int cls_of(const int* L, bool is64, int i) {
  int best = -0x7fffffff, c = 0;
  #pragma unroll
  for (int j = 0; j < 5; ++j) {
    int v = is64 ? L[i * 10 + 2 * j] : L[i * 5 + j];
    if (v > best) { best = v; c = j; }
  }
  return c;
}

// ---- Kernel 1: gram (blocks 0..68) + pack P (blocks 69..148) --------------
__global__ __launch_bounds__(256) void dsn_prep(const float* __restrict__ support,
                                                const int* __restrict__ labels,
                                                double* __restrict__ G,
                                                unsigned short* __restrict__ P) {
  int b = blockIdx.x;
  bool is64 = labels_int64(labels);

  if (b < 69) {                        // ---- gram: one wave per (w,a,b) pair
    int wid  = b * 4 + (threadIdx.x >> 6);
    int lane = threadIdx.x & 63;
    if (wid >= 275) return;
    int w = wid / 55, p = wid % 55;
    int a = 0;
    while (p >= 10 - a) { p -= 10 - a; a++; }
    int bb = a + p;

    int myc = (lane < 50) ? cls_of(labels, is64, lane) : -1;
    unsigned long long mask = __ballot(lane < 50 && myc == w);

    unsigned long long m = mask;
    for (int i = 0; i < a; ++i) m &= m - 1;
    int ia = __ffsll((unsigned long long)m) - 1;
    m = mask;
    for (int i = 0; i < bb; ++i) m &= m - 1;
    int ib = __ffsll((unsigned long long)m) - 1;

    const float* A = support + ia * 1024;
    const float* B = support + ib * 1024;
    double acc = 0.0;
    #pragma unroll
    for (int i = 0; i < 16; ++i) {
      int d = lane + 64 * i;
      acc += (double)A[d] * (double)B[d];
    }
    #pragma unroll
    for (int off = 32; off > 0; off >>= 1) acc += __shfl_xor(acc, off);
    if (lane == 0) {
      G[(w * 10 + a) * 10 + bb] = acc;
      G[(w * 10 + bb) * 10 + a] = acc;
    }
  } else {                             // ---- pack: one block per P row
    int r = b - 69;                    // 0..79
    int w = r >> 4, kk = r & 15;
    int t = threadIdx.x;
    unsigned short* Prow = P + r * 1024;
    if (kk >= 10) {                    // zero-pad rows (block-uniform)
      #pragma unroll
      for (int j = 0; j < 4; ++j) Prow[t + 256 * j] = 0;
      return;
    }
    __shared__ int sid;
    if (t < 64) {
      int myc = (t < 50) ? cls_of(labels, is64, t) : -1;
      unsigned long long mask = __ballot(t < 50 && myc == w);
      if (t == 0) {
        unsigned long long m = mask;
        for (int z = 0; z < kk; ++z) m &= m - 1;
        sid = __ffsll(m) - 1;
      }
    }
    __syncthreads();
    const float* src = support + (size_t)sid * 1024;
    #pragma unroll
    for (int j = 0; j < 4; ++j) Prow[t + 256 * j] = f2bf(src[t + 256 * j]);
  }
}

// ---- Kernel 2: Z-GEMM (blocks 5..1028, 1 wave each) + solve (blocks 0..4) --
// Solve per way: sweep-operator inverse (10 rank-1 steps) + v_min via 7
// diag-normalized squarings of Ginv + 2 refine matvecs. Single-wave block,
// 2 matrix entries per lane (t<50), all state in registers + small LDS.
__global__ __launch_bounds__(64) void dsn_zs(const float* __restrict__ query,
                                             const unsigned short* __restrict__ P,
                                             const double* __restrict__ G,
                                             float* __restrict__ Ghat,
                                             float* __restrict__ Z) {
  if (blockIdx.x < 5) {
    // ================= solve for way w (single wave, 64 threads) =========
    __shared__ float Gf[100], B[100];
    __shared__ float rowk[10], colk[10], vbuf[10], gvbuf[10];
    __shared__ float sbuf;
    __shared__ int   jmx;

    int w = blockIdx.x, t = threadIdx.x;
    bool act = (t < 50);
    int e0 = 2 * t, e1 = 2 * t + 1;
    int i0 = e0 / 10, j0 = e0 % 10;
    int i1 = e1 / 10, j1 = e1 % 10;
    if (!act) { e0 = 0; e1 = 1; i0 = 0; j0 = 0; i1 = 0; j1 = 1; }

    float a0 = 0.f, a1 = 0.f;
    if (act) {
      a0 = (float)G[w * 100 + e0];
      a1 = (float)G[w * 100 + e1];
      Gf[e0] = a0; Gf[e1] = a1;
    }
    __syncthreads();

    // ---- sweep-operator inverse: after 10 sweeps, a = -(G^{-1})_ij ----
    #pragma unroll 1
    for (int k = 0; k < 10; ++k) {
      if (act) {
        if (i0 == k) rowk[j0] = a0;
        if (i1 == k) rowk[j1] = a1;
        if (j0 == k) colk[i0] = a0;
        if (j1 == k) colk[i1] = a1;
      }
      __syncthreads();
      float dinv = 1.f / rowk[k];
      float r0 = rowk[j0], c0 = colk[i0];
      float r1 = rowk[j1], c1 = colk[i1];
      __syncthreads();                 // buffers reused next step
      if (act) {
        bool ik = (i0 == k), jk = (j0 == k);
        if (ik && jk)        a0 = -dinv;
        else if (ik || jk)   a0 = a0 * dinv;
        else                 a0 -= c0 * r0 * dinv;
        ik = (i1 == k); jk = (j1 == k);
        if (ik && jk)        a1 = -dinv;
        else if (ik || jk)   a1 = a1 * dinv;
        else                 a1 -= c1 * r1 * dinv;
      }
    }
    float ginv0 = -a0, ginv1 = -a1;    // G^{-1} entries (lane-owned)

    // ---- B = Ginv normalized to diag-max 1 ----
    if (act) { B[e0] = ginv0; B[e1] = ginv1; }
    __syncthreads();
    if (t == 0) {
      float m = B[0];
      #pragma unroll
      for (int k = 1; k < 10; ++k) m = fmaxf(m, B[k * 10 + k]);
      sbuf = 1.f / m;
    }
    __syncthreads();
    float rm0 = sbuf;
    if (act) { B[e0] = ginv0 * rm0; B[e1] = ginv1 * rm0; }
    __syncthreads();

    // ---- 7 squarings (PSD: max entry on diag -> cheap renorm) ----
    #pragma unroll 1
    for (int sq = 0; sq < 7; ++sq) {
      float s0 = 0.f, s1 = 0.f;
      if (act) {
        #pragma unroll
        for (int k = 0; k < 10; ++k) {
          s0 += B[i0 * 10 + k] * B[k * 10 + j0];
          s1 += B[i1 * 10 + k] * B[k * 10 + j1];
        }
      }
      __syncthreads();
      if (act) { B[e0] = s0; B[e1] = s1; }
      __syncthreads();
      if (t == 0) {
        float m = B[0];
        #pragma unroll
        for (int k = 1; k < 10; ++k) m = fmaxf(m, B[k * 10 + k]);
        sbuf = 1.f / m;
      }
      __syncthreads();
      float rm = sbuf;
      if (act) { B[e0] = s0 * rm; B[e1] = s1 * rm; }
      __syncthreads();
    }

    // ---- v = dominant column + 2 refinement matvecs ----
    if (t == 0) {
      int best = 0; float bv = B[0];
      #pragma unroll
      for (int k = 1; k < 10; ++k) {
        float dk = B[k * 10 + k];
        if (dk > bv) { bv = dk; best = k; }
      }
      jmx = best;
    }
    __syncthreads();
    if (t < 10) vbuf[t] = B[t * 10 + jmx];
    __syncthreads();
    #pragma unroll 1
    for (int rf = 0; rf < 2; ++rf) {
      float nv = 0.f;
      if (t < 10) {
        #pragma unroll
        for (int k = 0; k < 10; ++k) nv += B[t * 10 + k] * vbuf[k];
      }
      __syncthreads();
      if (t < 10) vbuf[t] = nv;
      __syncthreads();
    }

    // ---- denom = v^T G v (scale-invariant downstream) ----
    if (t < 10) {
      float gv = 0.f;
      #pragma unroll
      for (int k = 0; k < 10; ++k) gv += Gf[t * 10 + k] * vbuf[k];
      gvbuf[t] = gv;
    }
    __syncthreads();
    if (t == 0) {
      float denom = 0.f;
      #pragma unroll
      for (int k = 0; k < 10; ++k) denom += vbuf[k] * gvbuf[k];
      sbuf = 1.f / denom;
    }
    __syncthreads();
    float rden = sbuf;
    if (act) {
      Ghat[w * 100 + e0] = ginv0 - vbuf[i0] * vbuf[j0] * rden;
      Ghat[w * 100 + e1] = ginv1 - vbuf[i1] * vbuf[j1] * rden;
    }
    return;
  }

  // ================= GEMM: one wave, 16 queries =========================
  int wid  = blockIdx.x - 5;           // 0..1023
  int lane = threadIdx.x;
  int q0   = wid * 16;
  int qrow = lane & 15;
  int kbase = (lane >> 4) * 8;

  const float* qp = query + (size_t)(q0 + qrow) * 1024 + kbase;
  const unsigned short* up = P + qrow * 1024 + kbase;

  f32x4 acc[5];
  #pragma unroll
  for (int w = 0; w < 5; ++w) acc[w] = (f32x4){0.f, 0.f, 0.f, 0.f};

  #pragma unroll 4
  for (int kt = 0; kt < 32; ++kt) {
    const float* qk = qp + kt * 32;
    f32x4 lo = *(const f32x4*)qk;
    f32x4 hi = *(const f32x4*)(qk + 4);
    s16x8 bf;
    bf[0] = (short)f2bf(lo[0]); bf[1] = (short)f2bf(lo[1]);
    bf[2] = (short)f2bf(lo[2]); bf[3] = (short)f2bf(lo[3]);
    bf[4] = (short)f2bf(hi[0]); bf[5] = (short)f2bf(hi[1]);
    bf[6] = (short)f2bf(hi[2]); bf[7] = (short)f2bf(hi[3]);
    const unsigned short* uk = up + kt * 32;
    #pragma unroll
    for (int w = 0; w < 5; ++w) {
      s16x8 av = *(const s16x8*)(uk + w * 16384);   // row w*16 + qrow
      acc[w] = __builtin_amdgcn_mfma_f32_16x16x32_bf16(av, bf, acc[w], 0, 0, 0);
    }
  }

  // store Z: D[row=s][col=q]; row = (lane>>4)*4 + reg, col = lane&15 (m89)
  int rowbase = (lane >> 4) * 4;
  #pragma unroll
  for (int w = 0; w < 5; ++w) {
    #pragma unroll
    for (int r = 0; r < 4; ++r)
      Z[(size_t)(w * 16 + rowbase + r) * 16384 + q0 + qrow] = acc[w][r];
  }
}

// ---- Kernel 3: epilogue — quadratic forms + log_softmax -------------------
__global__ __launch_bounds__(256) void dsn_post(const float* __restrict__ Ghat,
                                                const float* __restrict__ Z,
                                                float* __restrict__ out) {
  __shared__ float Gh[500];
  int t = threadIdx.x;
  for (int i = t; i < 500; i += 256) Gh[i] = Ghat[i];
  __syncthreads();
  int q = blockIdx.x * 256 + t;

  float zv[50];
  #pragma unroll
  for (int w = 0; w < 5; ++w)
    #pragma unroll
    for (int s = 0; s < 10; ++s)
      zv[w * 10 + s] = Z[(size_t)(w * 16 + s) * 16384 + q];   // coalesced

  float sv[5];
  #pragma unroll
  for (int w = 0; w < 5; ++w) {
    float s = 0.f;
    #pragma unroll
    for (int i = 0; i < 10; ++i) {
      float gz = 0.f;
      #pragma unroll
      for (int j = 0; j < 10; ++j) gz += Gh[w * 100 + i * 10 + j] * zv[w * 10 + j];
      s += zv[w * 10 + i] * gz;
    }
    sv[w] = s;
  }
  float mx = fmaxf(fmaxf(fmaxf(sv[0], sv[1]), fmaxf(sv[2], sv[3])), sv[4]);
  float sum = 0.f;
  #pragma unroll
  for (int w = 0; w < 5; ++w) sum += expf(sv[w] - mx);
  float lse = mx + logf(sum);
  float* o = out + (size_t)q * 5;
  #pragma unroll
  for (int w = 0; w < 5; ++w) o[w] = sv[w] - lse;
}

extern "C" void kernel_launch(void* const* d_in, const int* in_sizes, int n_in,
                              void* d_out, int out_size, void* d_ws, size_t ws_size,
                              hipStream_t stream) {
  const float* support = (const float*)d_in[0];
  const int*   labels  = (const int*)d_in[1];
  const float* query   = (const float*)d_in[2];
  float* out = (float*)d_out;
  char* ws = (char*)d_ws;

  double*         G    = (double*)(ws + WS_G_OFF);
  float*          Ghat = (float*)(ws + WS_GH_OFF);
  unsigned short* P    = (unsigned short*)(ws + WS_P_OFF);
  float*          Z    = (float*)(ws + WS_Z_OFF);

  int nq = in_sizes[2] / 1024;          // 16384
  int zs_blocks = nq / 16 + 5;          // 1024 GEMM waves + 5 solve blocks
  int post_blocks = nq / 256;           // 64

  hipLaunchKernelGGL(dsn_prep, dim3(149), dim3(256), 0, stream, support, labels, G, P);
  hipLaunchKernelGGL(dsn_zs,   dim3(zs_blocks), dim3(64), 0, stream,
                     query, P, G, Ghat, Z);
  hipLaunchKernelGGL(dsn_post, dim3(post_blocks), dim3(256), 0, stream, Ghat, Z, out);
}

// Round 15
// 43.019 us; speedup vs baseline: 1.7764x; 1.0057x over previous
//
#include <hip/hip_runtime.h>
#include <stdint.h>

// DSN few-shot classifier, MI355X.
// out[q][w] = log_softmax_w( s_w ),  s_w = z_w^T Ghat_w z_w,
// z_w = M_w^T q (raw support dots),  Ghat = G^{-1} - v v^T/(v^T G v).
//
// R14: solve rebuilt as ZERO-LDS, ZERO-BARRIER, FULLY-UNROLLED register code.
// R1/R2/R3/R7 lesson (finally diagnosed): arrays live across ROLLED loops
// block SROA -> alloca -> scratch. Here every loop is unrolled (constant
// indices), comms via v_readlane (~4cyc, no lgkmcnt) -> chain ~3K cyc vs the
// LDS solve's ~10K latency-cycles. Solve = wave 0 of blocks 0..4 of the GEMM
// kernel (no barriers -> early-exit sibling waves safe); GEMM = R12's proven
// 4-wave-block shape at blocks 5..260.
//
// ws layout:
//   [0,      4000)   G    : 5*100 double
//   [4096,   6096)   Ghat : 5*100 float
//   [8192,   172032) P    : 80*1024 bf16 (way w rows 16w..16w+9; rest zero)
//   [262144, 5505024) Z   : [80][16384] float

typedef __attribute__((ext_vector_type(4))) float f32x4;
typedef __attribute__((ext_vector_type(8))) short s16x8;

#define WS_G_OFF    0
#define WS_GH_OFF   4096
#define WS_P_OFF    8192
#define WS_Z_OFF    262144

#define RDL(x, l) __uint_as_float(__builtin_amdgcn_readlane(__float_as_uint(x), (l)))

__device__ __forceinline__ unsigned short f2bf(float f) {
  unsigned int u = __float_as_uint(f);
  u += 0x7FFFu + ((u >> 16) & 1u);   // round-to-nearest-even
  return (unsigned short)(u >> 16);
}

// int64 vs int32 one-hot labels detection (validated R0).
__device__ __forceinline__ bool labels_int64(const int* L) {
  int cnt = 0; bool oddz = true;
  #pragma unroll
  for (int t = 0; t < 20; ++t) {
    int v = L[t];
    if (t & 1) { if (v) oddz = false; }
    else       { if (v) cnt++; }
  }
  return oddz && (cnt == 2);
}

__device__ __forceinline__ int cls_of(const int* L, bool is64, int i) {
  int best = -0x7fffffff, c = 0;
  #pragma unroll
  for (int j = 0; j < 5; ++j) {
    int v = is64 ? L[i * 10 + 2 * j] : L[i * 5 + j];
    if (v > best) { best = v; c = j; }
  }
  return c;
}

// ---- Kernel 1: gram (blocks 0..68) + pack P (blocks 69..148) --------------
__global__ __launch_bounds__(256) void dsn_prep(const float* __restrict__ support,
                                                const int* __restrict__ labels,
                                                double* __restrict__ G,
                                                unsigned short* __restrict__ P) {
  int b = blockIdx.x;
  bool is64 = labels_int64(labels);

  if (b < 69) {                        // ---- gram: one wave per (w,a,b) pair
    int wid  = b * 4 + (threadIdx.x >> 6);
    int lane = threadIdx.x & 63;
    if (wid >= 275) return;
    int w = wid / 55, p = wid % 55;
    int a = 0;
    while (p >= 10 - a) { p -= 10 - a; a++; }
    int bb = a + p;

    int myc = (lane < 50) ? cls_of(labels, is64, lane) : -1;
    unsigned long long mask = __ballot(lane < 50 && myc == w);

    unsigned long long m = mask;
    for (int i = 0; i < a; ++i) m &= m - 1;
    int ia = __ffsll((unsigned long long)m) - 1;
    m = mask;
    for (int i = 0; i < bb; ++i) m &= m - 1;
    int ib = __ffsll((unsigned long long)m) - 1;

    const float* A = support + ia * 1024;
    const float* B = support + ib * 1024;
    double acc = 0.0;
    #pragma unroll
    for (int i = 0; i < 16; ++i) {
      int d = lane + 64 * i;
      acc += (double)A[d] * (double)B[d];
    }
    #pragma unroll
    for (int off = 32; off > 0; off >>= 1) acc += __shfl_xor(acc, off);
    if (lane == 0) {
      G[(w * 10 + a) * 10 + bb] = acc;
      G[(w * 10 + bb) * 10 + a] = acc;
    }
  } else {                             // ---- pack: one block per P row
    int r = b - 69;                    // 0..79
    int w = r >> 4, kk = r & 15;
    int t = threadIdx.x;
    unsigned short* Prow = P + r * 1024;
    if (kk >= 10) {                    // zero-pad rows (block-uniform)
      #pragma unroll
      for (int j = 0; j < 4; ++j) Prow[t + 256 * j] = 0;
      return;
    }
    __shared__ int sid;
    if (t < 64) {
      int myc = (t < 50) ? cls_of(labels, is64, t) : -1;
      unsigned long long mask = __ballot(t < 50 && myc == w);
      if (t == 0) {
        unsigned long long m = mask;
        for (int z = 0; z < kk; ++z) m &= m - 1;
        sid = __ffsll(m) - 1;
      }
    }
    __syncthreads();
    const float* src = support + (size_t)sid * 1024;
    #pragma unroll
    for (int j = 0; j < 4; ++j) Prow[t + 256 * j] = f2bf(src[t + 256 * j]);
  }
}

// ---- Kernel 2: solve (blocks 0..4, wave 0) + Z-GEMM (blocks 5..260) --------
__global__ __launch_bounds__(256) void dsn_zs(const float* __restrict__ query,
                                              const unsigned short* __restrict__ P,
                                              const double* __restrict__ G,
                                              float* __restrict__ Ghat,
                                              float* __restrict__ Z) {
  if (blockIdx.x < 5) {
    // ====== solve, register-only, barrier-free (wave 0 of this block) =====
    if (threadIdx.x >= 64) return;     // waves 1-3 exit; no barriers anywhere
    int w = blockIdx.x;
    int li = threadIdx.x;              // lanes 0-9 hold rows; 10-63 compute garbage
    int rr = (li < 10) ? li : 0;
    const double* Gr = G + w * 100 + rr * 10;

    float o[10], g[10], h[10];
    #pragma unroll
    for (int j = 0; j < 10; ++j) {
      o[j] = (float)Gr[j];
      g[j] = o[j];
      h[j] = (li == j) ? 1.f : 0.f;
    }

    // Gauss-Jordan on [G | I] (SPD, no pivoting): h -> G^{-1} row li
    #pragma unroll
    for (int k = 0; k < 10; ++k) {
      float piv = 1.f / RDL(g[k], k);
      float pg[10], ph[10];
      #pragma unroll
      for (int j = 0; j < 10; ++j) {
        pg[j] = RDL(g[j], k) * piv;
        ph[j] = RDL(h[j], k) * piv;
      }
      float f = g[k];
      bool isk = (li == k);
      #pragma unroll
      for (int j = 0; j < 10; ++j) {
        g[j] = isk ? pg[j] : g[j] - f * pg[j];
        h[j] = isk ? ph[j] : h[j] - f * ph[j];
      }
    }

    // b = Ginv / diagmax
    float b[10];
    float d = h[0];
    #pragma unroll
    for (int k = 1; k < 10; ++k) d = (li == k) ? h[k] : d;
    float dm = RDL(d, 0);
    #pragma unroll
    for (int k = 1; k < 10; ++k) dm = fmaxf(dm, RDL(d, k));
    float rn = 1.f / dm;
    #pragma unroll
    for (int j = 0; j < 10; ++j) b[j] = h[j] * rn;

    // 7 diag-renormalized squarings: b -> dominant eigendirection of Ginv
    #pragma unroll
    for (int sq = 0; sq < 7; ++sq) {
      float c[10];
      #pragma unroll
      for (int j = 0; j < 10; ++j) {
        float s = 0.f;
        #pragma unroll
        for (int k = 0; k < 10; ++k) s += b[k] * RDL(b[j], k);
        c[j] = s;
      }
      float dd = c[0];
      #pragma unroll
      for (int k = 1; k < 10; ++k) dd = (li == k) ? c[k] : dd;
      float m = RDL(dd, 0);
      #pragma unroll
      for (int k = 1; k < 10; ++k) m = fmaxf(m, RDL(dd, k));
      float rm = 1.f / m;
      #pragma unroll
      for (int j = 0; j < 10; ++j) b[j] = c[j] * rm;
    }

    // v = dominant column (argmax diag) + 2 refine matvecs
    float db = b[0];
    #pragma unroll
    for (int k = 1; k < 10; ++k) db = (li == k) ? b[k] : db;
    int jmx = 0;
    float bv = RDL(db, 0);
    #pragma unroll
    for (int k = 1; k < 10; ++k) {
      float t2 = RDL(db, k);
      if (t2 > bv) { bv = t2; jmx = k; }   // uniform
    }
    float v = b[0];
    #pragma unroll
    for (int k = 1; k < 10; ++k) v = (jmx == k) ? b[k] : v;
    #pragma unroll
    for (int rf = 0; rf < 2; ++rf) {
      float nv = 0.f;
      #pragma unroll
      for (int k = 0; k < 10; ++k) nv += b[k] * RDL(v, k);
      v = nv;
    }

    // denom = v^T G v (scale-invariant); Ghat = Ginv - v v^T / denom
    float gv = 0.f;
    #pragma unroll
    for (int k = 0; k < 10; ++k) gv += o[k] * RDL(v, k);
    float tn = v * gv;
    float denom = RDL(tn, 0);
    #pragma unroll
    for (int k = 1; k < 10; ++k) denom += RDL(tn, k);
    float rden = 1.f / denom;
    if (li < 10) {
      #pragma unroll
      for (int j = 0; j < 10; ++j)
        Ghat[w * 100 + li * 10 + j] = h[j] - v * RDL(v, j) * rden;
    }
    return;
  }

  // ====== GEMM: 4 waves x 16 queries (R12 proven shape) ===================
  int wid  = (blockIdx.x - 5) * 4 + (threadIdx.x >> 6);
  int lane = threadIdx.x & 63;
  int q0   = wid * 16;
  int qrow = lane & 15;
  int kbase = (lane >> 4) * 8;

  const float* qp = query + (size_t)(q0 + qrow) * 1024 + kbase;
  const unsigned short* up = P + qrow * 1024 + kbase;

  f32x4 acc[5];
  #pragma unroll
  for (int w = 0; w < 5; ++w) acc[w] = (f32x4){0.f, 0.f, 0.f, 0.f};

  #pragma unroll 4
  for (int kt = 0; kt < 32; ++kt) {
    const float* qk = qp + kt * 32;
    f32x4 lo = *(const f32x4*)qk;
    f32x4 hi = *(const f32x4*)(qk + 4);
    s16x8 bf;
    bf[0] = (short)f2bf(lo[0]); bf[1] = (short)f2bf(lo[1]);
    bf[2] = (short)f2bf(lo[2]); bf[3] = (short)f2bf(lo[3]);
    bf[4] = (short)f2bf(hi[0]); bf[5] = (short)f2bf(hi[1]);
    bf[6] = (short)f2bf(hi[2]); bf[7] = (short)f2bf(hi[3]);
    const unsigned short* uk = up + kt * 32;
    #pragma unroll
    for (int w = 0; w < 5; ++w) {
      s16x8 av = *(const s16x8*)(uk + w * 16384);   // row w*16 + qrow
      acc[w] = __builtin_amdgcn_mfma_f32_16x16x32_bf16(av, bf, acc[w], 0, 0, 0);
    }
  }

  // store Z: D[row=s][col=q]; row = (lane>>4)*4 + reg, col = lane&15 (m89)
  int rowbase = (lane >> 4) * 4;
  #pragma unroll
  for (int w = 0; w < 5; ++w) {
    #pragma unroll
    for (int r = 0; r < 4; ++r)
      Z[(size_t)(w * 16 + rowbase + r) * 16384 + q0 + qrow] = acc[w][r];
  }
}

// ---- Kernel 3: epilogue — quadratic forms + log_softmax -------------------
__global__ __launch_bounds__(256) void dsn_post(const float* __restrict__ Ghat,
                                                const float* __restrict__ Z,
                                                float* __restrict__ out) {
  __shared__ float Gh[500];
  int t = threadIdx.x;
  for (int i = t; i < 500; i += 256) Gh[i] = Ghat[i];
  __syncthreads();
  int q = blockIdx.x * 256 + t;

  float zv[50];
  #pragma unroll
  for (int w = 0; w < 5; ++w)
    #pragma unroll
    for (int s = 0; s < 10; ++s)
      zv[w * 10 + s] = Z[(size_t)(w * 16 + s) * 16384 + q];   // coalesced

  float sv[5];
  #pragma unroll
  for (int w = 0; w < 5; ++w) {
    float s = 0.f;
    #pragma unroll
    for (int i = 0; i < 10; ++i) {
      float gz = 0.f;
      #pragma unroll
      for (int j = 0; j < 10; ++j) gz += Gh[w * 100 + i * 10 + j] * zv[w * 10 + j];
      s += zv[w * 10 + i] * gz;
    }
    sv[w] = s;
  }
  float mx = fmaxf(fmaxf(fmaxf(sv[0], sv[1]), fmaxf(sv[2], sv[3])), sv[4]);
  float sum = 0.f;
  #pragma unroll
  for (int w = 0; w < 5; ++w) sum += expf(sv[w] - mx);
  float lse = mx + logf(sum);
  float* o = out + (size_t)q * 5;
  #pragma unroll
  for (int w = 0; w < 5; ++w) o[w] = sv[w] - lse;
}

extern "C" void kernel_launch(void* const* d_in, const int* in_sizes, int n_in,
                              void* d_out, int out_size, void* d_ws, size_t ws_size,
                              hipStream_t stream) {
  const float* support = (const float*)d_in[0];
  const int*   labels  = (const int*)d_in[1];
  const float* query   = (const float*)d_in[2];
  float* out = (float*)d_out;
  char* ws = (char*)d_ws;

  double*         G    = (double*)(ws + WS_G_OFF);
  float*          Ghat = (float*)(ws + WS_GH_OFF);
  unsigned short* P    = (unsigned short*)(ws + WS_P_OFF);
  float*          Z    = (float*)(ws + WS_Z_OFF);

  int nq = in_sizes[2] / 1024;          // 16384
  int zs_blocks = nq / 64 + 5;          // 256 GEMM blocks + 5 solve blocks
  int post_blocks = nq / 256;           // 64

  hipLaunchKernelGGL(dsn_prep, dim3(149), dim3(256), 0, stream, support, labels, G, P);
  hipLaunchKernelGGL(dsn_zs,   dim3(zs_blocks), dim3(256), 0, stream,
                     query, P, G, Ghat, Z);
  hipLaunchKernelGGL(dsn_post, dim3(post_blocks), dim3(256), 0, stream, Ghat, Z, out);
}